// Round 9
// baseline (253.644 us; speedup 1.0000x reference)
//
#include <hip/hip_runtime.h>
#include <hip/hip_bf16.h>
#include <math.h>

// B=2, L=2048, D=1024, H=16, HD=64
#define NB_L 2048
#define GM 4096          // B*L rows
#define GN 3072          // 3*D cols
#define GK 1024
#define NROWS 65536      // B*H*L partial rows per split
#define SCALE_L2E 0.180336880f   // 0.125 * log2(e), folded into Q at GEMM epilogue

typedef float  f4v __attribute__((ext_vector_type(4)));
typedef short  s4v __attribute__((ext_vector_type(4)));
typedef short  s8v __attribute__((ext_vector_type(8)));

#define MFMA_16x16x32(a, b, c) __builtin_amdgcn_mfma_f32_16x16x32_bf16((a), (b), (c), 0, 0, 0)
#define MFMA_16x16x16(a, b, c) __builtin_amdgcn_mfma_f32_16x16x16bf16_1k((a), (b), (c), 0, 0, 0)

static __device__ __forceinline__ unsigned int bfpk(float a, float b) {
    __hip_bfloat162 h = __float22bfloat162_rn(float2{a, b});
    union { __hip_bfloat162 h2; unsigned int u; } cv; cv.h2 = h; return cv.u;
}
static __device__ __forceinline__ unsigned short bf1(float a) {
    union { __hip_bfloat16 h; unsigned short u; } cv; cv.h = __float2bfloat16(a); return cv.u;
}
static __device__ __forceinline__ float bf2f(unsigned short u) {
    union { unsigned int u; float f; } cv; cv.u = ((unsigned int)u) << 16; return cv.f;
}

// async global->LDS, 16B per lane
static __device__ __forceinline__ void gl_lds16(const ushort* g, ushort* l) {
    __builtin_amdgcn_global_load_lds((const __attribute__((address_space(1))) void*)g,
                                     (__attribute__((address_space(3))) void*)l, 16, 0, 0);
}

// ---------------------------------------------------------------------------
// Fused input prep: blocks [0,2048) convert X f32->bf16; blocks [2048,2816)
// convert+transpose W -> Wt [3072,1024] bf16 (k contiguous).
// ---------------------------------------------------------------------------
__global__ __launch_bounds__(256) void conv_fused(
    const float* __restrict__ X, const float* __restrict__ W,
    ushort* __restrict__ Xb, ushort* __restrict__ Wt)
{
    __shared__ __align__(16) ushort T[64][72];
    const int bid = blockIdx.x, t = threadIdx.x;
    if (bid < 2048) {
        const int i = bid * 256 + t;
        const float4 f0 = ((const float4*)X)[2 * i];
        const float4 f1 = ((const float4*)X)[2 * i + 1];
        uint4 u;
        u.x = bfpk(f0.x, f0.y); u.y = bfpk(f0.z, f0.w);
        u.z = bfpk(f1.x, f1.y); u.w = bfpk(f1.z, f1.w);
        ((uint4*)Xb)[i] = u;
    } else {
        const int wb = bid - 2048;                 // 0..767
        const int k0 = (wb & 15) * 64, n0 = (wb >> 4) * 64;
        {
            const int kr = t >> 2, nc0 = (t & 3) * 16;
            const float* src = W + (size_t)(k0 + kr) * GN + n0 + nc0;
#pragma unroll
            for (int u = 0; u < 4; ++u) {
                const float4 v = *(const float4*)(src + 4 * u);
                T[nc0 + 4 * u + 0][kr] = bf1(v.x);
                T[nc0 + 4 * u + 1][kr] = bf1(v.y);
                T[nc0 + 4 * u + 2][kr] = bf1(v.z);
                T[nc0 + 4 * u + 3][kr] = bf1(v.w);
            }
        }
        __syncthreads();
        {
            const int nr = t >> 2, kc0 = (t & 3) * 16;
            ushort* dst = Wt + (size_t)(n0 + nr) * GK + k0 + kc0;
            *(s8v*)dst       = *(const s8v*)&T[nr][kc0];
            *(s8v*)(dst + 8) = *(const s8v*)&T[nr][kc0 + 8];
        }
    }
}

// ---------------------------------------------------------------------------
// LDS-FREE bf16 MFMA GEMM: tile 128x128, BK=32, 256 thr (4 waves 2x2, wave
// tile 64x64). Both operands are k-contiguous, so each lane's MFMA fragment
// is one 16-B contiguous global load. No LDS, no barriers in the K-loop:
// register double-buffer with prefetch distance 1 (2x-unrolled, no reg
// copies). Loads have a full 16-MFMA phase to cover L2 latency; waves fully
// independent. Grid 24x32 = 768 blocks = 3/CU at ~160 VGPR.
// Epilogue writes attention-native per-head tensors:
//   Qh[bh][q][d]  (pre-scaled by 0.125*log2e)
//   Kh[bh][k][d ^ ((k&7)<<3)]     VT[bh][d][k ^ ((d&7)<<3)]
// ---------------------------------------------------------------------------
__global__ __launch_bounds__(256) void qkv_gemm_bf16(
    const ushort* __restrict__ Xb, const ushort* __restrict__ Wt,
    ushort* __restrict__ Qh, ushort* __restrict__ Kh, ushort* __restrict__ VT)
{
    const int tid = threadIdx.x;
    const int lane = tid & 63, w = tid >> 6;
    const int wr = w >> 1, wc = w & 1, lq = lane & 15, quad = lane >> 4;
    const int row0 = blockIdx.y * 128, col0 = blockIdx.x * 128;

    // per-lane fragment base pointers (k-offset quad*8)
    const ushort* pa[4];
    const ushort* pb[4];
#pragma unroll
    for (int g = 0; g < 4; ++g)
        pa[g] = Xb + (size_t)(row0 + wr * 64 + g * 16 + lq) * GK + quad * 8;
#pragma unroll
    for (int j = 0; j < 4; ++j)
        pb[j] = Wt + (size_t)(col0 + wc * 64 + j * 16 + lq) * GK + quad * 8;

    f4v acc[4][4];
#pragma unroll
    for (int g = 0; g < 4; ++g)
#pragma unroll
        for (int j = 0; j < 4; ++j) acc[g][j] = 0.f;

    s8v a0[4], b0[4], a1[4], b1[4];
#pragma unroll
    for (int g = 0; g < 4; ++g) { a0[g] = *(const s8v*)pa[g]; b0[g] = *(const s8v*)pb[g]; }

    for (int it = 0; it < 32; it += 2) {
        // prefetch odd phase (it+1)
        {
            const int k0 = (it + 1) * 32;
#pragma unroll
            for (int g = 0; g < 4; ++g) {
                a1[g] = *(const s8v*)(pa[g] + k0);
                b1[g] = *(const s8v*)(pb[g] + k0);
            }
        }
        // compute even phase
#pragma unroll
        for (int g = 0; g < 4; ++g)
#pragma unroll
            for (int j = 0; j < 4; ++j)
                acc[g][j] = MFMA_16x16x32(a0[g], b0[j], acc[g][j]);
        // prefetch next even phase (it+2)
        if (it + 2 < 32) {
            const int k0 = (it + 2) * 32;
#pragma unroll
            for (int g = 0; g < 4; ++g) {
                a0[g] = *(const s8v*)(pa[g] + k0);
                b0[g] = *(const s8v*)(pb[g] + k0);
            }
        }
        // compute odd phase
#pragma unroll
        for (int g = 0; g < 4; ++g)
#pragma unroll
            for (int j = 0; j < 4; ++j)
                acc[g][j] = MFMA_16x16x32(a1[g], b1[j], acc[g][j]);
    }

    // epilogue: col = col0 + wc*64 + j*16 + lq, row = row0 + wr*64 + g*16 + quad*4 + r
    const int part = blockIdx.x >> 3;   // 0=Q, 1=K, 2=V (block-uniform, 8 col-blocks each)
#pragma unroll
    for (int g = 0; g < 4; ++g)
#pragma unroll
        for (int j = 0; j < 4; ++j) {
            const int colp = (col0 & 1023) + wc * 64 + j * 16 + lq;
            const int hh = colp >> 6, d = colp & 63;
#pragma unroll
            for (int r = 0; r < 4; ++r) {
                const int row = row0 + wr * 64 + g * 16 + quad * 4 + r;
                const int b = row >> 11, tok = row & 2047;
                const int bh = b * 16 + hh;
                if (part == 0) {
                    Qh[((size_t)bh * 2048 + tok) * 64 + d] = bf1(acc[g][j][r] * SCALE_L2E);
                } else if (part == 1) {
                    Kh[((size_t)bh * 2048 + tok) * 64 + (d ^ ((tok & 7) << 3))] = bf1(acc[g][j][r]);
                } else {
                    VT[((size_t)bh * 64 + d) * 2048 + (tok ^ ((d & 7) << 3))] = bf1(acc[g][j][r]);
                }
            }
        }
}

// ---------------------------------------------------------------------------
// Flash attention, K-split=2, no running max. Block = 256 thr (4 waves),
// q-tile 128; wave w owns 32 q-rows. All K/V staging via global_load_lds
// (swizzled layouts baked in by the GEMM). Row-sums l via ones-row MFMA.
// Double-buffered, one barrier per tile. Dispatch: qt from bits 5-7
// complemented by bit 9 -> stride-256 CU residents {q,q,15-q,15-q}.
// ---------------------------------------------------------------------------
__global__ __launch_bounds__(256, 4) void attn_bf16(
    const ushort* __restrict__ Qh, const ushort* __restrict__ Kh,
    const ushort* __restrict__ VT, ushort* __restrict__ Opart, float* __restrict__ Lp)
{
    __shared__ __align__(16) ushort Ks[2][64 * 64];   // [krow][d^swz]
    __shared__ __align__(16) ushort Vt[2][64 * 64];   // [d][k^swz]

    const int x = blockIdx.x;
    const int bh = x & 31;
    const int qlow = (x >> 5) & 7;
    const int s = (x >> 8) & 1;
    const int x9 = (x >> 9) & 1;
    const int qt = x9 ? (15 - qlow) : qlow;

    const int tid = threadIdx.x;
    const int w = tid >> 6, lane = tid & 63;
    const int lq = lane & 15, quad = lane >> 4;
    const int kswz = (lq & 7) << 3;
    const int qrow_base = qt * 128 + w * 32;
    const int diag = 2 * qt + (w >> 1);

    s8v qf[2][2];
#pragma unroll
    for (int qg = 0; qg < 2; ++qg)
#pragma unroll
        for (int sb = 0; sb < 2; ++sb)
            qf[qg][sb] = *(const s8v*)(Qh + ((size_t)bh * 2048 + qrow_base + qg * 16 + lq) * 64
                                       + sb * 32 + quad * 8);

    f4v o[4][2];
#pragma unroll
    for (int dg = 0; dg < 4; ++dg)
#pragma unroll
        for (int qg = 0; qg < 2; ++qg) o[dg][qg] = 0.f;
    f4v lacc[2]; lacc[0] = 0.f; lacc[1] = 0.f;
    const s4v ones = { (short)0x3F80, (short)0x3F80, (short)0x3F80, (short)0x3F80 };

    const int kt_lo = s ? (qt + 1) : 0;
    const int kt_hi = s ? (2 * qt + 1) : qt;
    const int niter = kt_hi - kt_lo + 1;

    const ushort* kbase = Kh + (size_t)bh * 2048 * 64;
    const ushort* vbase = VT + (size_t)bh * 64 * 2048;
    const int g1 = tid, g2 = tid + 256;
    const int kr1 = g1 >> 3, ko1 = (g1 & 7) * 8;
    const int kr2 = g2 >> 3, ko2 = (g2 & 7) * 8;

    auto stage = [&](int kt, int bufi) {
        const ushort* kt_k = kbase + (size_t)kt * 64 * 64;
        const ushort* kt_v = vbase + kt * 64;
        gl_lds16(kt_k + kr1 * 64 + ko1,           &Ks[bufi][g1 * 8]);
        gl_lds16(kt_k + kr2 * 64 + ko2,           &Ks[bufi][g2 * 8]);
        gl_lds16(kt_v + (size_t)kr1 * 2048 + ko1, &Vt[bufi][g1 * 8]);
        gl_lds16(kt_v + (size_t)kr2 * 2048 + ko2, &Vt[bufi][g2 * 8]);
    };

    auto compute = [&](int ktc, int bufi) {
        if (ktc > diag) return;
        f4v st[4][2];
#pragma unroll
        for (int kg = 0; kg < 4; ++kg)
#pragma unroll
            for (int qg = 0; qg < 2; ++qg) st[kg][qg] = 0.f;
#pragma unroll
        for (int kg = 0; kg < 4; ++kg)
#pragma unroll
            for (int sb = 0; sb < 2; ++sb) {
                const s8v af = *(const s8v*)&Ks[bufi][(kg * 16 + lq) * 64
                                                     + ((sb * 32 + quad * 8) ^ kswz)];
#pragma unroll
                for (int qg = 0; qg < 2; ++qg)
                    st[kg][qg] = MFMA_16x16x32(af, qf[qg][sb], st[kg][qg]);
            }
        if (ktc == diag) {
#pragma unroll
            for (int kg = 0; kg < 4; ++kg)
#pragma unroll
                for (int qg = 0; qg < 2; ++qg) {
                    const int qrow = qrow_base + qg * 16 + lq;
#pragma unroll
                    for (int r = 0; r < 4; ++r)
                        if (ktc * 64 + kg * 16 + quad * 4 + r > qrow)
                            st[kg][qg][r] = -INFINITY;
                }
        }
#pragma unroll
        for (int kg = 0; kg < 4; ++kg)
#pragma unroll
            for (int qg = 0; qg < 2; ++qg)
#pragma unroll
                for (int r = 0; r < 4; ++r)
                    st[kg][qg][r] = exp2f(st[kg][qg][r]);
#pragma unroll
        for (int ks = 0; ks < 4; ++ks) {
            s4v pb[2];
#pragma unroll
            for (int qg = 0; qg < 2; ++qg) {
                union { s4v v; uint2 u; } c;
                c.u.x = bfpk(st[ks][qg][0], st[ks][qg][1]);
                c.u.y = bfpk(st[ks][qg][2], st[ks][qg][3]);
                pb[qg] = c.v;
            }
#pragma unroll
            for (int qg = 0; qg < 2; ++qg)
                lacc[qg] = MFMA_16x16x16(ones, pb[qg], lacc[qg]);
#pragma unroll
            for (int dg = 0; dg < 4; ++dg) {
                const s4v va = *(const s4v*)&Vt[bufi][(dg * 16 + lq) * 64
                                                     + ((ks * 16 + quad * 4) ^ kswz)];
#pragma unroll
                for (int qg = 0; qg < 2; ++qg)
                    o[dg][qg] = MFMA_16x16x16(va, pb[qg], o[dg][qg]);
            }
        }
    };

    stage(kt_lo, 0);
    for (int i = 0; i < niter; ++i) {
        const int cur = i & 1;
        __syncthreads();
        if (i + 1 < niter) stage(kt_lo + i + 1, cur ^ 1);
        compute(kt_lo + i, cur);
    }

#pragma unroll
    for (int qg = 0; qg < 2; ++qg) {
        const size_t prow = (size_t)(s * 32 + bh) * 2048 + qrow_base + qg * 16 + lq;
#pragma unroll
        for (int dg = 0; dg < 4; ++dg) {
            const int d = dg * 16 + quad * 4;
            uint2 u;
            u.x = bfpk(o[dg][qg][0], o[dg][qg][1]);
            u.y = bfpk(o[dg][qg][2], o[dg][qg][3]);
            *(uint2*)&Opart[prow * 64 + d] = u;
        }
        if (quad == 0) Lp[prow] = lacc[qg][0];
    }
}

// ---------------------------------------------------------------------------
// Combine the two K-split partials -> final f32 output [B, L, D].
// ---------------------------------------------------------------------------
__global__ __launch_bounds__(256) void attn_combine(
    const ushort* __restrict__ Opart, const float* __restrict__ Lp, float* __restrict__ Out)
{
    const int id = blockIdx.x * 256 + threadIdx.x;
    const int row = id >> 4, c4 = (id & 15) * 4;
    const float l0 = Lp[row], l1 = Lp[row + NROWS];
    const float inv = 1.0f / (l0 + l1);

    const s4v a = *(const s4v*)&Opart[(size_t)row * 64 + c4];
    const s4v c = *(const s4v*)&Opart[(size_t)(row + NROWS) * 64 + c4];
    float4 v;
    v.x = (bf2f((unsigned short)a[0]) + bf2f((unsigned short)c[0])) * inv;
    v.y = (bf2f((unsigned short)a[1]) + bf2f((unsigned short)c[1])) * inv;
    v.z = (bf2f((unsigned short)a[2]) + bf2f((unsigned short)c[2])) * inv;
    v.w = (bf2f((unsigned short)a[3]) + bf2f((unsigned short)c[3])) * inv;

    const int bh = row >> 11, qrow = row & 2047;
    const int b = bh >> 4, h = bh & 15;
    *(float4*)(Out + ((size_t)(b * 2048 + qrow)) * 1024 + h * 64 + c4) = v;
}

// ---------------------------------------------------------------------------
extern "C" void kernel_launch(void* const* d_in, const int* in_sizes, int n_in,
                              void* d_out, int out_size, void* d_ws, size_t ws_size,
                              hipStream_t stream)
{
    const float* x  = (const float*)d_in[0];  // [2,2048,1024] f32
    const float* wq = (const float*)d_in[1];  // [1024,3072] f32
    float* out = (float*)d_out;               // [2,2048,1024] f32

    const size_t HEADTEN = (size_t)32 * 2048 * 64;   // 8.4 MB bf16 each
    ushort* wsp = (ushort*)d_ws;
    ushort* qh = wsp;
    ushort* kh = qh + HEADTEN;
    ushort* vt = kh + HEADTEN;
    ushort* xb = vt + HEADTEN;           // dead after GEMM
    ushort* wt = xb + (size_t)GM * GK;   // dead after GEMM
    ushort* opart = xb;                                        // overlays xb/wt
    float*  lp    = (float*)(opart + (size_t)2 * NROWS * 64);

    conv_fused<<<2816, 256, 0, stream>>>(x, wq, xb, wt);
    qkv_gemm_bf16<<<dim3(24, 32), 256, 0, stream>>>(xb, wt, qh, kh, vt);
    attn_bf16<<<1024, 256, 0, stream>>>(qh, kh, vt, opart, lp);
    attn_combine<<<NROWS * 16 / 256, 256, 0, stream>>>(opart, lp, out);
}

// Round 10
// 189.108 us; speedup vs baseline: 1.3413x; 1.3413x over previous
//
#include <hip/hip_runtime.h>
#include <hip/hip_bf16.h>
#include <math.h>

// B=2, L=2048, D=1024, H=16, HD=64
#define NB_L 2048
#define GM 4096          // B*L rows
#define GN 3072          // 3*D cols
#define GK 1024
#define NROWS 65536      // B*H*L partial rows per split
#define SCALE_L2E 0.180336880f   // 0.125 * log2(e), folded into Q at GEMM epilogue

typedef float  f4v __attribute__((ext_vector_type(4)));
typedef short  s4v __attribute__((ext_vector_type(4)));
typedef short  s8v __attribute__((ext_vector_type(8)));

#define MFMA_16x16x32(a, b, c) __builtin_amdgcn_mfma_f32_16x16x32_bf16((a), (b), (c), 0, 0, 0)
#define MFMA_16x16x16(a, b, c) __builtin_amdgcn_mfma_f32_16x16x16bf16_1k((a), (b), (c), 0, 0, 0)

static __device__ __forceinline__ unsigned int bfpk(float a, float b) {
    __hip_bfloat162 h = __float22bfloat162_rn(float2{a, b});
    union { __hip_bfloat162 h2; unsigned int u; } cv; cv.h2 = h; return cv.u;
}
static __device__ __forceinline__ unsigned short bf1(float a) {
    union { __hip_bfloat16 h; unsigned short u; } cv; cv.h = __float2bfloat16(a); return cv.u;
}
static __device__ __forceinline__ float bf2f(unsigned short u) {
    union { unsigned int u; float f; } cv; cv.u = ((unsigned int)u) << 16; return cv.f;
}

// async global->LDS, 16B per lane
static __device__ __forceinline__ void gl_lds16(const ushort* g, ushort* l) {
    __builtin_amdgcn_global_load_lds((const __attribute__((address_space(1))) void*)g,
                                     (__attribute__((address_space(3))) void*)l, 16, 0, 0);
}

// ---------------------------------------------------------------------------
// Fused input prep: blocks [0,2048) convert X f32->bf16; blocks [2048,2816)
// convert+transpose W -> Wt [3072,1024] bf16 (k contiguous).
// ---------------------------------------------------------------------------
__global__ __launch_bounds__(256) void conv_fused(
    const float* __restrict__ X, const float* __restrict__ W,
    ushort* __restrict__ Xb, ushort* __restrict__ Wt)
{
    __shared__ __align__(16) ushort T[64][72];
    const int bid = blockIdx.x, t = threadIdx.x;
    if (bid < 2048) {
        const int i = bid * 256 + t;
        const float4 f0 = ((const float4*)X)[2 * i];
        const float4 f1 = ((const float4*)X)[2 * i + 1];
        uint4 u;
        u.x = bfpk(f0.x, f0.y); u.y = bfpk(f0.z, f0.w);
        u.z = bfpk(f1.x, f1.y); u.w = bfpk(f1.z, f1.w);
        ((uint4*)Xb)[i] = u;
    } else {
        const int wb = bid - 2048;                 // 0..767
        const int k0 = (wb & 15) * 64, n0 = (wb >> 4) * 64;
        {
            const int kr = t >> 2, nc0 = (t & 3) * 16;
            const float* src = W + (size_t)(k0 + kr) * GN + n0 + nc0;
#pragma unroll
            for (int u = 0; u < 4; ++u) {
                const float4 v = *(const float4*)(src + 4 * u);
                T[nc0 + 4 * u + 0][kr] = bf1(v.x);
                T[nc0 + 4 * u + 1][kr] = bf1(v.y);
                T[nc0 + 4 * u + 2][kr] = bf1(v.z);
                T[nc0 + 4 * u + 3][kr] = bf1(v.w);
            }
        }
        __syncthreads();
        {
            const int nr = t >> 2, kc0 = (t & 3) * 16;
            ushort* dst = Wt + (size_t)(n0 + nr) * GK + k0 + kc0;
            *(s8v*)dst       = *(const s8v*)&T[nr][kc0];
            *(s8v*)(dst + 8) = *(const s8v*)&T[nr][kc0 + 8];
        }
    }
}

// ---------------------------------------------------------------------------
// bf16 MFMA GEMM (R7 structure, measured 67 us): 128x128 tile, BK=32, 256 thr,
// dbuf glds16 staging, ONE barrier/iter. 1-D grid 768 with XCD REGION SWIZZLE:
// XCD j (= linear block id % 8) owns an 8-row x 12-col region of the 32x24
// block grid, so concurrently-resident blocks on one XCD share A-chunks (x12)
// and B-chunks (x8) -> staging loads hit that XCD's L2 (~200 cyc) instead of
// cold L3 (~600+), which one 16-MFMA compute phase can cover.
// Epilogue writes attention-native per-head tensors:
//   Qh[bh][q][d]  (pre-scaled by 0.125*log2e)
//   Kh[bh][k][d ^ ((k&7)<<3)]     VT[bh][d][k ^ ((d&7)<<3)]
// ---------------------------------------------------------------------------
__global__ __launch_bounds__(256) void qkv_gemm_bf16(
    const ushort* __restrict__ Xb, const ushort* __restrict__ Wt,
    ushort* __restrict__ Qh, ushort* __restrict__ Kh, ushort* __restrict__ VT)
{
    __shared__ __align__(16) ushort As[2][4][128][8];
    __shared__ __align__(16) ushort Bs[2][4][128][8];
    const int tid = threadIdx.x;

    // region swizzle: l%8 = XCD hint; region = 8 row-tiles x 12 col-tiles
    const int l = blockIdx.x;            // 0..767
    const int j = l & 7, t = l >> 3;     // t in [0,96)
    const int lr = t & 7, lc = t >> 3;   // lc in [0,12)
    const int ytile = ((j >> 1) << 3) + lr;      // 0..31
    const int xtile = (j & 1) * 12 + lc;         // 0..23
    const int row0 = ytile * 128, col0 = xtile * 128;

    const int mA = tid & 127, k2a = tid >> 7;
    const int lane = tid & 63, w = tid >> 6;
    const int wr = w >> 1, wc = w & 1, lq = lane & 15, quad = lane >> 4;

    f4v acc[4][4];
#pragma unroll
    for (int g = 0; g < 4; ++g)
#pragma unroll
        for (int j2 = 0; j2 < 4; ++j2) acc[g][j2] = 0.f;

    const ushort* gA = Xb + (size_t)(row0 + mA) * GK + k2a * 8;
    const ushort* gB = Wt + (size_t)(col0 + mA) * GK + k2a * 8;

    gl_lds16(gA,      &As[0][k2a][mA][0]);
    gl_lds16(gA + 16, &As[0][k2a + 2][mA][0]);
    gl_lds16(gB,      &Bs[0][k2a][mA][0]);
    gl_lds16(gB + 16, &Bs[0][k2a + 2][mA][0]);

    for (int it = 0; it < 32; ++it) {
        const int cur = it & 1, nxt = cur ^ 1;
        __syncthreads();
        if (it + 1 < 32) {
            const int k0 = (it + 1) * 32;
            gl_lds16(gA + k0,      &As[nxt][k2a][mA][0]);
            gl_lds16(gA + k0 + 16, &As[nxt][k2a + 2][mA][0]);
            gl_lds16(gB + k0,      &Bs[nxt][k2a][mA][0]);
            gl_lds16(gB + k0 + 16, &Bs[nxt][k2a + 2][mA][0]);
        }
        s8v af[4], bfr[4];
#pragma unroll
        for (int g = 0; g < 4; ++g) af[g]   = *(const s8v*)&As[cur][quad][wr * 64 + g * 16 + lq][0];
#pragma unroll
        for (int j2 = 0; j2 < 4; ++j2) bfr[j2] = *(const s8v*)&Bs[cur][quad][wc * 64 + j2 * 16 + lq][0];
#pragma unroll
        for (int g = 0; g < 4; ++g)
#pragma unroll
            for (int j2 = 0; j2 < 4; ++j2)
                acc[g][j2] = MFMA_16x16x32(af[g], bfr[j2], acc[g][j2]);
    }

    // epilogue: col = col0 + wc*64 + j*16 + lq, row = row0 + wr*64 + g*16 + quad*4 + r
    const int part = xtile >> 3;   // 0=Q, 1=K, 2=V (block-uniform)
#pragma unroll
    for (int g = 0; g < 4; ++g)
#pragma unroll
        for (int j2 = 0; j2 < 4; ++j2) {
            const int colp = (col0 & 1023) + wc * 64 + j2 * 16 + lq;
            const int hh = colp >> 6, d = colp & 63;
#pragma unroll
            for (int r = 0; r < 4; ++r) {
                const int row = row0 + wr * 64 + g * 16 + quad * 4 + r;
                const int b = row >> 11, tok = row & 2047;
                const int bh = b * 16 + hh;
                if (part == 0) {
                    Qh[((size_t)bh * 2048 + tok) * 64 + d] = bf1(acc[g][j2][r] * SCALE_L2E);
                } else if (part == 1) {
                    Kh[((size_t)bh * 2048 + tok) * 64 + (d ^ ((tok & 7) << 3))] = bf1(acc[g][j2][r]);
                } else {
                    VT[((size_t)bh * 64 + d) * 2048 + (tok ^ ((d & 7) << 3))] = bf1(acc[g][j2][r]);
                }
            }
        }
}

// ---------------------------------------------------------------------------
// Flash attention, K-split=2, no running max. Block = 256 thr (4 waves),
// q-tile 128; wave w owns 32 q-rows. All K/V staging via global_load_lds
// (swizzled layouts baked in by the GEMM). Row-sums l via ones-row MFMA.
// Double-buffered, one barrier per tile. Dispatch: qt from bits 5-7
// complemented by bit 9 -> stride-256 CU residents {q,q,15-q,15-q}.
// ---------------------------------------------------------------------------
__global__ __launch_bounds__(256, 4) void attn_bf16(
    const ushort* __restrict__ Qh, const ushort* __restrict__ Kh,
    const ushort* __restrict__ VT, ushort* __restrict__ Opart, float* __restrict__ Lp)
{
    __shared__ __align__(16) ushort Ks[2][64 * 64];   // [krow][d^swz]
    __shared__ __align__(16) ushort Vt[2][64 * 64];   // [d][k^swz]

    const int x = blockIdx.x;
    const int bh = x & 31;
    const int qlow = (x >> 5) & 7;
    const int s = (x >> 8) & 1;
    const int x9 = (x >> 9) & 1;
    const int qt = x9 ? (15 - qlow) : qlow;

    const int tid = threadIdx.x;
    const int w = tid >> 6, lane = tid & 63;
    const int lq = lane & 15, quad = lane >> 4;
    const int kswz = (lq & 7) << 3;
    const int qrow_base = qt * 128 + w * 32;
    const int diag = 2 * qt + (w >> 1);

    s8v qf[2][2];
#pragma unroll
    for (int qg = 0; qg < 2; ++qg)
#pragma unroll
        for (int sb = 0; sb < 2; ++sb)
            qf[qg][sb] = *(const s8v*)(Qh + ((size_t)bh * 2048 + qrow_base + qg * 16 + lq) * 64
                                       + sb * 32 + quad * 8);

    f4v o[4][2];
#pragma unroll
    for (int dg = 0; dg < 4; ++dg)
#pragma unroll
        for (int qg = 0; qg < 2; ++qg) o[dg][qg] = 0.f;
    f4v lacc[2]; lacc[0] = 0.f; lacc[1] = 0.f;
    const s4v ones = { (short)0x3F80, (short)0x3F80, (short)0x3F80, (short)0x3F80 };

    const int kt_lo = s ? (qt + 1) : 0;
    const int kt_hi = s ? (2 * qt + 1) : qt;
    const int niter = kt_hi - kt_lo + 1;

    const ushort* kbase = Kh + (size_t)bh * 2048 * 64;
    const ushort* vbase = VT + (size_t)bh * 64 * 2048;
    const int g1 = tid, g2 = tid + 256;
    const int kr1 = g1 >> 3, ko1 = (g1 & 7) * 8;
    const int kr2 = g2 >> 3, ko2 = (g2 & 7) * 8;

    auto stage = [&](int kt, int bufi) {
        const ushort* kt_k = kbase + (size_t)kt * 64 * 64;
        const ushort* kt_v = vbase + kt * 64;
        gl_lds16(kt_k + kr1 * 64 + ko1,           &Ks[bufi][g1 * 8]);
        gl_lds16(kt_k + kr2 * 64 + ko2,           &Ks[bufi][g2 * 8]);
        gl_lds16(kt_v + (size_t)kr1 * 2048 + ko1, &Vt[bufi][g1 * 8]);
        gl_lds16(kt_v + (size_t)kr2 * 2048 + ko2, &Vt[bufi][g2 * 8]);
    };

    auto compute = [&](int ktc, int bufi) {
        if (ktc > diag) return;
        f4v st[4][2];
#pragma unroll
        for (int kg = 0; kg < 4; ++kg)
#pragma unroll
            for (int qg = 0; qg < 2; ++qg) st[kg][qg] = 0.f;
#pragma unroll
        for (int kg = 0; kg < 4; ++kg)
#pragma unroll
            for (int sb = 0; sb < 2; ++sb) {
                const s8v af = *(const s8v*)&Ks[bufi][(kg * 16 + lq) * 64
                                                     + ((sb * 32 + quad * 8) ^ kswz)];
#pragma unroll
                for (int qg = 0; qg < 2; ++qg)
                    st[kg][qg] = MFMA_16x16x32(af, qf[qg][sb], st[kg][qg]);
            }
        if (ktc == diag) {
#pragma unroll
            for (int kg = 0; kg < 4; ++kg)
#pragma unroll
                for (int qg = 0; qg < 2; ++qg) {
                    const int qrow = qrow_base + qg * 16 + lq;
#pragma unroll
                    for (int r = 0; r < 4; ++r)
                        if (ktc * 64 + kg * 16 + quad * 4 + r > qrow)
                            st[kg][qg][r] = -INFINITY;
                }
        }
#pragma unroll
        for (int kg = 0; kg < 4; ++kg)
#pragma unroll
            for (int qg = 0; qg < 2; ++qg)
#pragma unroll
                for (int r = 0; r < 4; ++r)
                    st[kg][qg][r] = exp2f(st[kg][qg][r]);
#pragma unroll
        for (int ks = 0; ks < 4; ++ks) {
            s4v pb[2];
#pragma unroll
            for (int qg = 0; qg < 2; ++qg) {
                union { s4v v; uint2 u; } c;
                c.u.x = bfpk(st[ks][qg][0], st[ks][qg][1]);
                c.u.y = bfpk(st[ks][qg][2], st[ks][qg][3]);
                pb[qg] = c.v;
            }
#pragma unroll
            for (int qg = 0; qg < 2; ++qg)
                lacc[qg] = MFMA_16x16x16(ones, pb[qg], lacc[qg]);
#pragma unroll
            for (int dg = 0; dg < 4; ++dg) {
                const s4v va = *(const s4v*)&Vt[bufi][(dg * 16 + lq) * 64
                                                     + ((ks * 16 + quad * 4) ^ kswz)];
#pragma unroll
                for (int qg = 0; qg < 2; ++qg)
                    o[dg][qg] = MFMA_16x16x16(va, pb[qg], o[dg][qg]);
            }
        }
    };

    stage(kt_lo, 0);
    for (int i = 0; i < niter; ++i) {
        const int cur = i & 1;
        __syncthreads();
        if (i + 1 < niter) stage(kt_lo + i + 1, cur ^ 1);
        compute(kt_lo + i, cur);
    }

#pragma unroll
    for (int qg = 0; qg < 2; ++qg) {
        const size_t prow = (size_t)(s * 32 + bh) * 2048 + qrow_base + qg * 16 + lq;
#pragma unroll
        for (int dg = 0; dg < 4; ++dg) {
            const int d = dg * 16 + quad * 4;
            uint2 u;
            u.x = bfpk(o[dg][qg][0], o[dg][qg][1]);
            u.y = bfpk(o[dg][qg][2], o[dg][qg][3]);
            *(uint2*)&Opart[prow * 64 + d] = u;
        }
        if (quad == 0) Lp[prow] = lacc[qg][0];
    }
}

// ---------------------------------------------------------------------------
// Combine the two K-split partials -> final f32 output [B, L, D].
// ---------------------------------------------------------------------------
__global__ __launch_bounds__(256) void attn_combine(
    const ushort* __restrict__ Opart, const float* __restrict__ Lp, float* __restrict__ Out)
{
    const int id = blockIdx.x * 256 + threadIdx.x;
    const int row = id >> 4, c4 = (id & 15) * 4;
    const float l0 = Lp[row], l1 = Lp[row + NROWS];
    const float inv = 1.0f / (l0 + l1);

    const s4v a = *(const s4v*)&Opart[(size_t)row * 64 + c4];
    const s4v c = *(const s4v*)&Opart[(size_t)(row + NROWS) * 64 + c4];
    float4 v;
    v.x = (bf2f((unsigned short)a[0]) + bf2f((unsigned short)c[0])) * inv;
    v.y = (bf2f((unsigned short)a[1]) + bf2f((unsigned short)c[1])) * inv;
    v.z = (bf2f((unsigned short)a[2]) + bf2f((unsigned short)c[2])) * inv;
    v.w = (bf2f((unsigned short)a[3]) + bf2f((unsigned short)c[3])) * inv;

    const int bh = row >> 11, qrow = row & 2047;
    const int b = bh >> 4, h = bh & 15;
    *(float4*)(Out + ((size_t)(b * 2048 + qrow)) * 1024 + h * 64 + c4) = v;
}

// ---------------------------------------------------------------------------
extern "C" void kernel_launch(void* const* d_in, const int* in_sizes, int n_in,
                              void* d_out, int out_size, void* d_ws, size_t ws_size,
                              hipStream_t stream)
{
    const float* x  = (const float*)d_in[0];  // [2,2048,1024] f32
    const float* wq = (const float*)d_in[1];  // [1024,3072] f32
    float* out = (float*)d_out;               // [2,2048,1024] f32

    const size_t HEADTEN = (size_t)32 * 2048 * 64;   // 8.4 MB bf16 each
    ushort* wsp = (ushort*)d_ws;
    ushort* qh = wsp;
    ushort* kh = qh + HEADTEN;
    ushort* vt = kh + HEADTEN;
    ushort* xb = vt + HEADTEN;           // dead after GEMM
    ushort* wt = xb + (size_t)GM * GK;   // dead after GEMM
    ushort* opart = xb;                                        // overlays xb/wt
    float*  lp    = (float*)(opart + (size_t)2 * NROWS * 64);

    conv_fused<<<2816, 256, 0, stream>>>(x, wq, xb, wt);
    qkv_gemm_bf16<<<768, 256, 0, stream>>>(xb, wt, qh, kh, vt);
    attn_bf16<<<1024, 256, 0, stream>>>(qh, kh, vt, opart, lp);
    attn_combine<<<NROWS * 16 / 256, 256, 0, stream>>>(opart, lp, out);
}